// Round 2
// baseline (1155.301 us; speedup 1.0000x reference)
//
#include <hip/hip_runtime.h>
#include <math.h>

#define HID 2048
#define NH 16
#define HD 128
#define INTERD 8192
#define SEQL 2048
#define NBATCH 2
#define NTOK (NBATCH*SEQL)

typedef float f32x4 __attribute__((ext_vector_type(4)));
typedef __bf16 bfx8 __attribute__((ext_vector_type(8)));

__device__ __forceinline__ float bf2f(unsigned short u){
  union { float f; unsigned v; } c; c.v = ((unsigned)u)<<16; return c.f;
}
__device__ __forceinline__ unsigned short f2bf(float f){
  union { float f; unsigned v; } c; c.f = f;
  unsigned r = c.v + 0x7FFFu + ((c.v>>16)&1u);   // RNE
  return (unsigned short)(r>>16);
}

// ---------------- sentinel: marks "workspace too small" unambiguously ----------------
__global__ void k_sentinel(float* out){ out[0] = 1.0e9f; }

// ---------------- fp32 -> bf16 conversion (weights) ----------------
__global__ __launch_bounds__(256) void k_cvt(const float* __restrict__ in,
                                             unsigned short* __restrict__ out, int n4){
  int i = blockIdx.x*256 + threadIdx.x;
  if(i >= n4) return;
  float4 v = reinterpret_cast<const float4*>(in)[i];
  ushort4 o;
  o.x = f2bf(v.x); o.y = f2bf(v.y); o.z = f2bf(v.z); o.w = f2bf(v.w);
  reinterpret_cast<ushort4*>(out)[i] = o;
}

// ---------------- RMSNorm (fp32 in) -> bf16 out ----------------
__global__ __launch_bounds__(256) void k_rmsnorm(const float* __restrict__ x,
                                                 const float* __restrict__ w,
                                                 unsigned short* __restrict__ out){
  int row = blockIdx.x, t = threadIdx.x;
  const float4* xr = reinterpret_cast<const float4*>(x + (size_t)row*HID);
  float4 a = xr[2*t], b = xr[2*t+1];
  float ss = a.x*a.x+a.y*a.y+a.z*a.z+a.w*a.w + b.x*b.x+b.y*b.y+b.z*b.z+b.w*b.w;
  #pragma unroll
  for(int o=1;o<64;o<<=1) ss += __shfl_xor(ss, o);
  __shared__ float red[4];
  if((t&63)==0) red[t>>6] = ss;
  __syncthreads();
  float sc = rsqrtf((red[0]+red[1]+red[2]+red[3])*(1.0f/HID) + 1e-6f);
  const float4* wr = reinterpret_cast<const float4*>(w);
  float4 wa = wr[2*t], wb = wr[2*t+1];
  ushort4 o1, o2;
  o1.x=f2bf(a.x*sc*wa.x); o1.y=f2bf(a.y*sc*wa.y); o1.z=f2bf(a.z*sc*wa.z); o1.w=f2bf(a.w*sc*wa.w);
  o2.x=f2bf(b.x*sc*wb.x); o2.y=f2bf(b.y*sc*wb.y); o2.z=f2bf(b.z*sc*wb.z); o2.w=f2bf(b.w*sc*wb.w);
  ushort4* orow = reinterpret_cast<ushort4*>(out + (size_t)row*HID);
  orow[2*t] = o1; orow[2*t+1] = o2;
}

// ---------------- RoPE tables: cos/sin [SEQL][64] ----------------
__global__ void k_ropetab(float* __restrict__ cs, float* __restrict__ sn){
  int s = blockIdx.x, j = threadIdx.x;   // 64 threads
  float invf = powf(10000.0f, -(float)j*(1.0f/64.0f));
  float ang = (float)s * invf;
  float c, si;
  sincosf(ang, &si, &c);
  cs[s*64+j] = c; sn[s*64+j] = si;
}

// ---------------- RoPE apply in-place on bf16 [B,S,H,D]; scale folds 1/sqrt(D) for Q ---
__global__ __launch_bounds__(256) void k_rope(unsigned short* qk,
                                              const float* __restrict__ cs,
                                              const float* __restrict__ sn, float scale){
  int gid = blockIdx.x*256 + threadIdx.x;
  int j = gid & 63;
  int rh = gid >> 6;               // tok*NH + h
  int s = (rh >> 4) & (SEQL-1);
  unsigned short* base = qk + (size_t)rh*HD;
  float c = cs[s*64+j], sv = sn[s*64+j];
  float x1 = bf2f(base[j]), x2 = bf2f(base[j+64]);
  base[j]    = f2bf((x1*c - x2*sv)*scale);
  base[j+64] = f2bf((x2*c + x1*sv)*scale);
}

// ---------------- GEMM: C[M,N] = A[M,K] * W[N,K]^T  (bf16 in, fp32 acc) ----------------
// EPI 0: write bf16.  EPI 1: write fp32 = resid + acc.  EPI 2: write bf16 = silu(g)*acc (g=gbuf, may alias out).
// 256 thr = 4 waves; tile 128x128, BK=64; wave-tile 128x32 (8x2 frags of 16x16).
template<int EPI>
__global__ __launch_bounds__(256) void k_gemm(const unsigned short* __restrict__ A,
                                              const unsigned short* __restrict__ W,
                                              void* out, const float* __restrict__ resid,
                                              const unsigned short* gbuf,
                                              int M, int N, int K){
  __shared__ unsigned short Alds[128*64];
  __shared__ unsigned short Wlds[128*64];
  int nwg = gridDim.x;
  int bid = blockIdx.x;
  bid = (bid & 7)*(nwg>>3) + (bid>>3);     // XCD-aware swizzle (nwg % 8 == 0 for all our grids)
  int nbn = N >> 7;
  int bm0 = (bid / nbn) << 7, bn0 = (bid % nbn) << 7;
  int t = threadIdx.x, w = t>>6, l = t&63, lr = l&15, lg = l>>4;
  int srow = t>>3, sch = t&7;

  f32x4 z = {0.f,0.f,0.f,0.f};
  f32x4 acc[8][2];
  #pragma unroll
  for(int i=0;i<8;i++){ acc[i][0]=z; acc[i][1]=z; }

  for(int k0=0;k0<K;k0+=64){
    __syncthreads();                        // protect previous tile's reads
    #pragma unroll
    for(int p=0;p<4;p++){
      int r = srow + 32*p;
      bfx8 va = *reinterpret_cast<const bfx8*>(A + (size_t)(bm0+r)*K + k0 + sch*8);
      bfx8 vb = *reinterpret_cast<const bfx8*>(W + (size_t)(bn0+r)*K + k0 + sch*8);
      // XOR-swizzled store: 16B chunk index ^ (row&7) -> conflict-free b128 reads
      *reinterpret_cast<bfx8*>(reinterpret_cast<char*>(Alds) + r*128 + ((sch ^ (r&7))<<4)) = va;
      *reinterpret_cast<bfx8*>(reinterpret_cast<char*>(Wlds) + r*128 + ((sch ^ (r&7))<<4)) = vb;
    }
    __syncthreads();
    #pragma unroll
    for(int ks=0;ks<2;ks++){
      bfx8 af[8], bfr[2];
      #pragma unroll
      for(int fm=0;fm<8;fm++){
        int row = fm*16 + lr;
        af[fm] = *reinterpret_cast<const bfx8*>(reinterpret_cast<const char*>(Alds)
                   + row*128 + ((((ks<<2)+lg) ^ (row&7))<<4));
      }
      #pragma unroll
      for(int fn=0;fn<2;fn++){
        int row = (w<<5) + fn*16 + lr;
        bfr[fn] = *reinterpret_cast<const bfx8*>(reinterpret_cast<const char*>(Wlds)
                   + row*128 + ((((ks<<2)+lg) ^ (row&7))<<4));
      }
      #pragma unroll
      for(int fm=0;fm<8;fm++)
        #pragma unroll
        for(int fn=0;fn<2;fn++)
          acc[fm][fn] = __builtin_amdgcn_mfma_f32_16x16x32_bf16(af[fm], bfr[fn], acc[fm][fn], 0,0,0);
    }
  }
  // epilogue: C row = bm0+fm*16+lg*4+r ; col = bn0+w*32+fn*16+lr
  #pragma unroll
  for(int fm=0;fm<8;fm++){
    #pragma unroll
    for(int r=0;r<4;r++){
      int row = bm0 + fm*16 + (lg<<2) + r;
      #pragma unroll
      for(int fn=0;fn<2;fn++){
        int col = bn0 + (w<<5) + fn*16 + lr;
        size_t idx = (size_t)row*N + col;
        float v = acc[fm][fn][r];
        if(EPI==0){
          reinterpret_cast<unsigned short*>(out)[idx] = f2bf(v);
        } else if(EPI==1){
          reinterpret_cast<float*>(out)[idx] = resid[idx] + v;
        } else {
          float g = bf2f(gbuf[idx]);
          float sg = g / (1.0f + __expf(-g));
          reinterpret_cast<unsigned short*>(out)[idx] = f2bf(sg*v);
        }
      }
    }
  }
}

// ---------------- Flash attention, causal. Q/K/V/O bf16 [B,S,H,D]. Q pre-scaled. -------
// 256 thr = 4 waves; block: 64 q-rows (16/wave); KV tiles of 32.
// Swapped QK^T: S' = mfma(K,Q) -> lane holds col q = l&15, rows = keys.
__global__ __launch_bounds__(256) void k_attn(const unsigned short* __restrict__ Q,
                                              const unsigned short* __restrict__ Kb,
                                              const unsigned short* __restrict__ Vb,
                                              unsigned short* __restrict__ O){
  __shared__ unsigned short Klds[32*128];     // swizzled row-major [32][128]
  __shared__ unsigned short Vlds[128*40];     // transposed, padded: Vt[d][key], stride 40
  __shared__ unsigned short Plds[4][16*40];   // per-wave P[q][key], stride 40

  int bid = blockIdx.x;
  int qt = bid & 31, bh = bid >> 5;
  int h = bh & 15, b = bh >> 4;
  int q0 = qt << 6;
  int t = threadIdx.x, w = t>>6, l = t&63, lr = l&15, lg = l>>4;
  int q0w = q0 + (w<<4);

  bfx8 qf[4];
  const unsigned short* qrow = Q + ((size_t)((b*SEQL + q0w + lr)*NH) + h)*HD;
  #pragma unroll
  for(int ds=0;ds<4;ds++) qf[ds] = *reinterpret_cast<const bfx8*>(qrow + ds*32 + lg*8);

  f32x4 z = {0.f,0.f,0.f,0.f};
  f32x4 oacc[8];
  #pragma unroll
  for(int i=0;i<8;i++) oacc[i] = z;
  float m_run = -1e30f, l_run = 0.f;

  int skey = t>>3, schk = t&7;
  int ntile = (q0>>5) + 2;                   // causal: tiles with k0 <= q0+63
  for(int tl=0; tl<ntile; ++tl){
    int k0 = tl << 5;
    __syncthreads();
    #pragma unroll
    for(int p=0;p<2;p++){
      int ch = schk*2 + p;                   // 16B chunk 0..15 of the 128-elem row
      const unsigned short* ksrc = Kb + ((size_t)((b*SEQL + k0 + skey)*NH) + h)*HD + ch*8;
      const unsigned short* vsrc = Vb + ((size_t)((b*SEQL + k0 + skey)*NH) + h)*HD + ch*8;
      bfx8 kv = *reinterpret_cast<const bfx8*>(ksrc);
      *reinterpret_cast<bfx8*>(reinterpret_cast<char*>(Klds)
          + skey*256 + ((ch ^ (skey&7))<<4)) = kv;   // swizzled (XOR low 3 bits)
      bfx8 vv = *reinterpret_cast<const bfx8*>(vsrc);
      union { bfx8 v; unsigned short u[8]; } uv; uv.v = vv;
      #pragma unroll
      for(int j=0;j<8;j++) Vlds[(ch*8+j)*40 + skey] = uv.u[j];
    }
    __syncthreads();

    f32x4 sA = z, sB = z;
    #pragma unroll
    for(int ds=0;ds<4;ds++){
      int cha = (ds<<2) + lg;
      bfx8 ka = *reinterpret_cast<const bfx8*>(reinterpret_cast<const char*>(Klds)
                  + lr*256 + ((cha ^ (lr&7))<<4));
      bfx8 kb = *reinterpret_cast<const bfx8*>(reinterpret_cast<const char*>(Klds)
                  + (16+lr)*256 + ((cha ^ (lr&7))<<4));
      sA = __builtin_amdgcn_mfma_f32_16x16x32_bf16(ka, qf[ds], sA, 0,0,0);
      sB = __builtin_amdgcn_mfma_f32_16x16x32_bf16(kb, qf[ds], sB, 0,0,0);
    }
    int qg = q0w + lr;
    float p[8];
    float mx = -1e30f;
    #pragma unroll
    for(int r=0;r<4;r++){
      int kga = k0 + (lg<<2) + r;
      float va = (kga    <= qg) ? sA[r] : -1e30f;
      float vb = (kga+16 <= qg) ? sB[r] : -1e30f;
      p[r] = va; p[4+r] = vb;
      mx = fmaxf(mx, fmaxf(va, vb));
    }
    mx = fmaxf(mx, __shfl_xor(mx,16));
    mx = fmaxf(mx, __shfl_xor(mx,32));       // per-q max (q = lr)
    float m_new = fmaxf(m_run, mx);
    float fac = __expf(m_run - m_new);
    float ts = 0.f;
    #pragma unroll
    for(int i=0;i<8;i++){ p[i] = __expf(p[i]-m_new); ts += p[i]; }
    ts += __shfl_xor(ts,16); ts += __shfl_xor(ts,32);
    l_run = l_run*fac + ts;
    m_run = m_new;
    // write P'[q][key] (bf16) to per-wave LDS
    unsigned pk0 = (unsigned)f2bf(p[0]) | ((unsigned)f2bf(p[1])<<16);
    unsigned pk1 = (unsigned)f2bf(p[2]) | ((unsigned)f2bf(p[3])<<16);
    unsigned pk2 = (unsigned)f2bf(p[4]) | ((unsigned)f2bf(p[5])<<16);
    unsigned pk3 = (unsigned)f2bf(p[6]) | ((unsigned)f2bf(p[7])<<16);
    char* pb = reinterpret_cast<char*>(&Plds[w][0]) + lr*80 + lg*8;
    *reinterpret_cast<uint2*>(pb)      = make_uint2(pk0, pk1);  // keys lg*4..+3
    *reinterpret_cast<uint2*>(pb + 32) = make_uint2(pk2, pk3);  // keys 16+lg*4..+3
    // rescale O (frag rows = q = lg*4+r; stats live at lane q)
    float facr[4];
    #pragma unroll
    for(int r=0;r<4;r++) facr[r] = __shfl(fac, (lg<<2)+r);
    #pragma unroll
    for(int db=0;db<8;db++){
      f32x4 o = oacc[db];
      o[0]*=facr[0]; o[1]*=facr[1]; o[2]*=facr[2]; o[3]*=facr[3];
      oacc[db] = o;
    }
    __syncthreads();   // make P writes visible (also keeps cross-lane LDS order safe)
    bfx8 pf = *reinterpret_cast<const bfx8*>(reinterpret_cast<const char*>(&Plds[w][0])
                + lr*80 + lg*16);
    #pragma unroll
    for(int db=0;db<8;db++){
      bfx8 vf = *reinterpret_cast<const bfx8*>(reinterpret_cast<const char*>(Vlds)
                  + (db*16+lr)*80 + lg*16);
      oacc[db] = __builtin_amdgcn_mfma_f32_16x16x32_bf16(pf, vf, oacc[db], 0,0,0);
    }
  }
  float lsr[4];
  #pragma unroll
  for(int r=0;r<4;r++) lsr[r] = 1.0f / __shfl(l_run, (lg<<2)+r);
  #pragma unroll
  for(int db=0;db<8;db++){
    #pragma unroll
    for(int r=0;r<4;r++){
      int row = q0w + (lg<<2) + r;
      O[((size_t)((b*SEQL + row)*NH) + h)*HD + db*16 + lr] = f2bf(oacc[db][r]*lsr[r]);
    }
  }
}

// ---------------- host launcher ----------------
// Workspace plan (129 MB total, overlaid; all same-stream so ordering is safe):
//   Wbuf : 32 MB  bf16 weight staging, reused for every GEMM (cvt -> gemm pairs)
//   hb   : 16 MB  rmsnorm out (attn), later rmsnorm out (ffn)
//   qb   : 16 MB ┐
//   kb   : 16 MB │ 64 MB contiguous; after O-proj all dead -> gb (gate/h_mid) overlays
//   vb   : 16 MB │
//   aob  : 16 MB ┘
//   x1   : 32 MB  fp32 residual stream after attention
//   cos/sin tables: 1 MB
extern "C" void kernel_launch(void* const* d_in, const int* in_sizes, int n_in,
                              void* d_out, int out_size, void* d_ws, size_t ws_size,
                              hipStream_t stream){
  const float* x   = (const float*)d_in[0];
  const float* anw = (const float*)d_in[1];
  const float* qw  = (const float*)d_in[2];
  const float* kw  = (const float*)d_in[3];
  const float* vw  = (const float*)d_in[4];
  const float* ow  = (const float*)d_in[5];
  const float* fnw = (const float*)d_in[6];
  const float* gw  = (const float*)d_in[7];
  const float* uw  = (const float*)d_in[8];
  const float* dw  = (const float*)d_in[9];
  float* out = (float*)d_out;

  char* ws = (char*)d_ws;
  size_t off = 0;
  auto alloc = [&](size_t bytes)->char*{ char* p = ws + off; off += (bytes + 255) & ~(size_t)255; return p; };
  unsigned short* Wbuf = (unsigned short*)alloc((size_t)INTERD*HID*2);   // 32 MB, reused
  unsigned short* hb   = (unsigned short*)alloc((size_t)NTOK*HID*2);     // 16 MB
  unsigned short* qb   = (unsigned short*)alloc((size_t)NTOK*HID*2);     // 16 MB
  unsigned short* kb   = (unsigned short*)alloc((size_t)NTOK*HID*2);     // 16 MB
  unsigned short* vb   = (unsigned short*)alloc((size_t)NTOK*HID*2);     // 16 MB
  unsigned short* aob  = (unsigned short*)alloc((size_t)NTOK*HID*2);     // 16 MB
  float*          x1   = (float*)alloc((size_t)NTOK*HID*4);              // 32 MB
  float*          cosb = (float*)alloc((size_t)SEQL*64*4);
  float*          sinb = (float*)alloc((size_t)SEQL*64*4);
  unsigned short* gb   = qb;   // 64 MB overlay: qb|kb|vb|aob, dead after O-proj
  if(ws_size < off){ k_sentinel<<<1,1,0,stream>>>(out); return; }

  k_ropetab<<<SEQL, 64, 0, stream>>>(cosb, sinb);

  // ---- attention sublayer ----
  k_rmsnorm<<<NTOK, 256, 0, stream>>>(x, anw, hb);
  k_cvt<<<HID*HID/1024, 256, 0, stream>>>(qw, Wbuf, HID*HID/4);
  k_gemm<0><<<(NTOK/128)*(HID/128), 256, 0, stream>>>(hb, Wbuf, qb, nullptr, nullptr, NTOK, HID, HID);
  k_cvt<<<HID*HID/1024, 256, 0, stream>>>(kw, Wbuf, HID*HID/4);
  k_gemm<0><<<(NTOK/128)*(HID/128), 256, 0, stream>>>(hb, Wbuf, kb, nullptr, nullptr, NTOK, HID, HID);
  k_cvt<<<HID*HID/1024, 256, 0, stream>>>(vw, Wbuf, HID*HID/4);
  k_gemm<0><<<(NTOK/128)*(HID/128), 256, 0, stream>>>(hb, Wbuf, vb, nullptr, nullptr, NTOK, HID, HID);
  k_rope<<<(NTOK*NH*64)/256, 256, 0, stream>>>(qb, cosb, sinb, 0.08838834764831845f); // 1/sqrt(128)
  k_rope<<<(NTOK*NH*64)/256, 256, 0, stream>>>(kb, cosb, sinb, 1.0f);
  k_attn<<<(SEQL/64)*NBATCH*NH, 256, 0, stream>>>(qb, kb, vb, aob);
  k_cvt<<<HID*HID/1024, 256, 0, stream>>>(ow, Wbuf, HID*HID/4);
  k_gemm<1><<<(NTOK/128)*(HID/128), 256, 0, stream>>>(aob, Wbuf, x1, x, nullptr, NTOK, HID, HID);

  // ---- MLP sublayer ----
  k_rmsnorm<<<NTOK, 256, 0, stream>>>(x1, fnw, hb);
  k_cvt<<<INTERD*HID/1024, 256, 0, stream>>>(gw, Wbuf, INTERD*HID/4);
  k_gemm<0><<<(NTOK/128)*(INTERD/128), 256, 0, stream>>>(hb, Wbuf, gb, nullptr, nullptr, NTOK, INTERD, HID);
  k_cvt<<<INTERD*HID/1024, 256, 0, stream>>>(uw, Wbuf, INTERD*HID/4);
  k_gemm<2><<<(NTOK/128)*(INTERD/128), 256, 0, stream>>>(hb, Wbuf, gb, nullptr, gb, NTOK, INTERD, HID); // h_mid = silu(g)*u in place
  k_cvt<<<INTERD*HID/1024, 256, 0, stream>>>(dw, Wbuf, INTERD*HID/4);
  k_gemm<1><<<(NTOK/128)*(HID/128), 256, 0, stream>>>(gb, Wbuf, out, x1, nullptr, NTOK, HID, INTERD);
}

// Round 3
// 998.120 us; speedup vs baseline: 1.1575x; 1.1575x over previous
//
#include <hip/hip_runtime.h>
#include <math.h>

#define HID 2048
#define NH 16
#define HD 128
#define INTERD 8192
#define SEQL 2048
#define NBATCH 2
#define NTOK (NBATCH*SEQL)

typedef float f32x4 __attribute__((ext_vector_type(4)));
typedef __bf16 bfx8 __attribute__((ext_vector_type(8)));

#if defined(__has_builtin)
#if __has_builtin(__builtin_amdgcn_global_load_lds)
#define HAS_GLL 1
#else
#define HAS_GLL 0
#endif
#else
#define HAS_GLL 0
#endif

__device__ __forceinline__ float bf2f(unsigned short u){
  union { float f; unsigned v; } c; c.v = ((unsigned)u)<<16; return c.f;
}
__device__ __forceinline__ unsigned short f2bf(float f){
  union { float f; unsigned v; } c; c.f = f;
  unsigned r = c.v + 0x7FFFu + ((c.v>>16)&1u);   // RNE
  return (unsigned short)(r>>16);
}

#if HAS_GLL
// async global->LDS, 16B per lane. LDS dest = wave-uniform base + lane*16 (m104/m108).
__device__ __forceinline__ void gll16(const unsigned short* g, void* l){
  __builtin_amdgcn_global_load_lds(
      (const __attribute__((address_space(1))) unsigned int*)(size_t)(const void*)g,
      (__attribute__((address_space(3))) unsigned int*)(unsigned int)(size_t)l,
      16, 0, 0);
}
#endif

// ---------------- sentinel: marks "workspace too small" unambiguously ----------------
__global__ void k_sentinel(float* out){ out[0] = 1.0e9f; }

// ---------------- fp32 -> bf16 conversion (weights) ----------------
__global__ __launch_bounds__(256) void k_cvt(const float* __restrict__ in,
                                             unsigned short* __restrict__ out, int n4){
  int i = blockIdx.x*256 + threadIdx.x;
  if(i >= n4) return;
  float4 v = reinterpret_cast<const float4*>(in)[i];
  ushort4 o;
  o.x = f2bf(v.x); o.y = f2bf(v.y); o.z = f2bf(v.z); o.w = f2bf(v.w);
  reinterpret_cast<ushort4*>(out)[i] = o;
}

// ---------------- RMSNorm (fp32 in) -> bf16 out ----------------
__global__ __launch_bounds__(256) void k_rmsnorm(const float* __restrict__ x,
                                                 const float* __restrict__ w,
                                                 unsigned short* __restrict__ out){
  int row = blockIdx.x, t = threadIdx.x;
  const float4* xr = reinterpret_cast<const float4*>(x + (size_t)row*HID);
  float4 a = xr[2*t], b = xr[2*t+1];
  float ss = a.x*a.x+a.y*a.y+a.z*a.z+a.w*a.w + b.x*b.x+b.y*b.y+b.z*b.z+b.w*b.w;
  #pragma unroll
  for(int o=1;o<64;o<<=1) ss += __shfl_xor(ss, o);
  __shared__ float red[4];
  if((t&63)==0) red[t>>6] = ss;
  __syncthreads();
  float sc = rsqrtf((red[0]+red[1]+red[2]+red[3])*(1.0f/HID) + 1e-6f);
  const float4* wr = reinterpret_cast<const float4*>(w);
  float4 wa = wr[2*t], wb = wr[2*t+1];
  ushort4 o1, o2;
  o1.x=f2bf(a.x*sc*wa.x); o1.y=f2bf(a.y*sc*wa.y); o1.z=f2bf(a.z*sc*wa.z); o1.w=f2bf(a.w*sc*wa.w);
  o2.x=f2bf(b.x*sc*wb.x); o2.y=f2bf(b.y*sc*wb.y); o2.z=f2bf(b.z*sc*wb.z); o2.w=f2bf(b.w*sc*wb.w);
  ushort4* orow = reinterpret_cast<ushort4*>(out + (size_t)row*HID);
  orow[2*t] = o1; orow[2*t+1] = o2;
}

// ---------------- RoPE tables: cos/sin [SEQL][64] ----------------
__global__ void k_ropetab(float* __restrict__ cs, float* __restrict__ sn){
  int s = blockIdx.x, j = threadIdx.x;   // 64 threads
  float invf = powf(10000.0f, -(float)j*(1.0f/64.0f));
  float ang = (float)s * invf;
  float c, si;
  sincosf(ang, &si, &c);
  cs[s*64+j] = c; sn[s*64+j] = si;
}

// ---------------- RoPE apply in-place on bf16 [B,S,H,D]; scale folds 1/sqrt(D) for Q ---
__global__ __launch_bounds__(256) void k_rope(unsigned short* qk,
                                              const float* __restrict__ cs,
                                              const float* __restrict__ sn, float scale){
  int gid = blockIdx.x*256 + threadIdx.x;
  int j = gid & 63;
  int rh = gid >> 6;               // tok*NH + h
  int s = (rh >> 4) & (SEQL-1);
  unsigned short* base = qk + (size_t)rh*HD;
  float c = cs[s*64+j], sv = sn[s*64+j];
  float x1 = bf2f(base[j]), x2 = bf2f(base[j+64]);
  base[j]    = f2bf((x1*c - x2*sv)*scale);
  base[j+64] = f2bf((x2*c + x1*sv)*scale);
}

// ---------------- V transpose: VT[b,h,d,s] <- V[b,s,h,d] (bf16) ----------------
// one block per (b, h, 64-wide s-block); 256 threads
__global__ __launch_bounds__(256) void k_transpose_v(const unsigned short* __restrict__ V,
                                                     unsigned short* __restrict__ VT){
  __shared__ unsigned short T[64*136];   // [s][d], stride 136 hw
  int bid = blockIdx.x;
  int sb = bid & 31, h = (bid>>5) & 15, b = bid>>9;
  int t = threadIdx.x;
  int s0 = sb<<6;
  int sl = t>>2, dc = (t&3)<<5;
  const unsigned short* src = V + ((size_t)((b*SEQL + s0 + sl)*NH) + h)*HD + dc;
  #pragma unroll
  for(int p=0;p<4;p++){
    bfx8 v = *reinterpret_cast<const bfx8*>(src + p*8);
    *reinterpret_cast<bfx8*>(&T[sl*136 + dc + p*8]) = v;
  }
  __syncthreads();
  int d = t>>1, sh = (t&1)<<5;
  unsigned short* dst = VT + ((size_t)((b*NH + h)*HD + d))*SEQL + s0 + sh;
  #pragma unroll
  for(int p=0;p<4;p++){
    union { bfx8 v; unsigned short u[8]; } o;
    #pragma unroll
    for(int j=0;j<8;j++) o.u[j] = T[(sh + p*8 + j)*136 + d];
    *reinterpret_cast<bfx8*>(dst + p*8) = o.v;
  }
}

// ---------------- GEMM: C[M,N] = A[M,K] * W[N,K]^T  (bf16 in, fp32 acc) ----------------
// EPI 0: write bf16.  EPI 1: write fp32 = resid + acc.  EPI 2: write bf16 = silu(g)*acc.
// 256 thr = 4 waves; tile 128x128, BK=64; wave-tile 128x32 (8x2 frags of 16x16).
// Staging via global_load_lds w=16: linear LDS dest, inverse-XOR-swizzled global source.
template<int EPI>
__global__ __launch_bounds__(256) void k_gemm(const unsigned short* __restrict__ A,
                                              const unsigned short* __restrict__ W,
                                              void* out, const float* __restrict__ resid,
                                              const unsigned short* gbuf,
                                              int M, int N, int K){
  __shared__ unsigned short Alds[128*64];
  __shared__ unsigned short Wlds[128*64];
  int nwg = gridDim.x;
  int bid = blockIdx.x;
  bid = (bid & 7)*(nwg>>3) + (bid>>3);     // XCD-aware swizzle (nwg % 8 == 0 always here)
  int nbn = N >> 7;
  int bm0 = (bid / nbn) << 7, bn0 = (bid % nbn) << 7;
  int t = threadIdx.x, w = t>>6, l = t&63, lr = l&15, lg = l>>4;

  f32x4 z = {0.f,0.f,0.f,0.f};
  f32x4 acc[8][2];
  #pragma unroll
  for(int i=0;i<8;i++){ acc[i][0]=z; acc[i][1]=z; }

#if HAS_GLL
  int lrow = l>>3;                          // 0..7 within the 8-row chunk
  int lcs  = (l&7) ^ lrow;                  // pre-swizzled source chunk (involution)
#else
  int srow = t>>3, sch = t&7;
#endif

  for(int k0=0;k0<K;k0+=64){
    __syncthreads();                        // protect previous tile's reads
#if HAS_GLL
    #pragma unroll
    for(int p=0;p<4;p++){
      int br = (w<<5) + (p<<3);             // 8 rows per wave-pass
      gll16(A + (size_t)(bm0+br+lrow)*K + k0 + lcs*8, (char*)Alds + br*128);
      gll16(W + (size_t)(bn0+br+lrow)*K + k0 + lcs*8, (char*)Wlds + br*128);
    }
#else
    #pragma unroll
    for(int p=0;p<4;p++){
      int r = srow + 32*p;
      bfx8 va = *reinterpret_cast<const bfx8*>(A + (size_t)(bm0+r)*K + k0 + sch*8);
      bfx8 vb = *reinterpret_cast<const bfx8*>(W + (size_t)(bn0+r)*K + k0 + sch*8);
      *reinterpret_cast<bfx8*>(reinterpret_cast<char*>(Alds) + r*128 + ((sch ^ (r&7))<<4)) = va;
      *reinterpret_cast<bfx8*>(reinterpret_cast<char*>(Wlds) + r*128 + ((sch ^ (r&7))<<4)) = vb;
    }
#endif
    __syncthreads();
    #pragma unroll
    for(int ks=0;ks<2;ks++){
      bfx8 af[8], bfr[2];
      #pragma unroll
      for(int fm=0;fm<8;fm++){
        int row = fm*16 + lr;
        af[fm] = *reinterpret_cast<const bfx8*>(reinterpret_cast<const char*>(Alds)
                   + row*128 + ((((ks<<2)+lg) ^ (row&7))<<4));
      }
      #pragma unroll
      for(int fn=0;fn<2;fn++){
        int row = (w<<5) + fn*16 + lr;
        bfr[fn] = *reinterpret_cast<const bfx8*>(reinterpret_cast<const char*>(Wlds)
                   + row*128 + ((((ks<<2)+lg) ^ (row&7))<<4));
      }
      #pragma unroll
      for(int fm=0;fm<8;fm++)
        #pragma unroll
        for(int fn=0;fn<2;fn++)
          acc[fm][fn] = __builtin_amdgcn_mfma_f32_16x16x32_bf16(af[fm], bfr[fn], acc[fm][fn], 0,0,0);
    }
  }
  // epilogue: C row = bm0+fm*16+lg*4+r ; col = bn0+w*32+fn*16+lr
  #pragma unroll
  for(int fm=0;fm<8;fm++){
    #pragma unroll
    for(int r=0;r<4;r++){
      int row = bm0 + fm*16 + (lg<<2) + r;
      #pragma unroll
      for(int fn=0;fn<2;fn++){
        int col = bn0 + (w<<5) + fn*16 + lr;
        size_t idx = (size_t)row*N + col;
        float v = acc[fm][fn][r];
        if(EPI==0){
          reinterpret_cast<unsigned short*>(out)[idx] = f2bf(v);
        } else if(EPI==1){
          reinterpret_cast<float*>(out)[idx] = resid[idx] + v;
        } else {
          float g = bf2f(gbuf[idx]);
          float sg = g / (1.0f + __expf(-g));
          reinterpret_cast<unsigned short*>(out)[idx] = f2bf(sg*v);
        }
      }
    }
  }
}

// ---------------- Flash attention, causal. Q/K bf16 [B,S,H,D] (RoPE'd, Q pre-scaled),
// V^T bf16 [B,H,D,S]. 256 thr = 4 waves; block: 64 q (16/wave); KV tiles of 64.
// Swapped QK^T: mfma(K,Q) -> lane holds q-col = l&15, key rows.
__global__ __launch_bounds__(256) void k_attn(const unsigned short* __restrict__ Q,
                                              const unsigned short* __restrict__ Kb,
                                              const unsigned short* __restrict__ VT,
                                              unsigned short* __restrict__ O){
  __shared__ unsigned short Klds[64*128];     // [key][d] swizzled: 16 chunks/row, c^(row&7)
  __shared__ unsigned short Vlds[128*64];     // [d][key] swizzled: 8 chunks/row, c^(row&7)
  __shared__ unsigned short Plds[4][16*72];   // per-wave P[q][key], stride 72 hw

  int bid = blockIdx.x;
  // XCD-aware decode: each XCD owns 4 bh (K+VT working set = 4MB = one L2);
  // heavy q-tiles scheduled first (qt descending) to reduce tail imbalance.
  int xcd = bid & 7, idx = bid >> 3;
  int bh = xcd*4 + (idx & 3);
  int qt = 31 - (idx >> 2);
  int h = bh & 15, b = bh >> 4;
  int q0 = qt << 6;
  int t = threadIdx.x, w = t>>6, l = t&63, lr = l&15, lg = l>>4;
  int q0w = q0 + (w<<4);

  bfx8 qf[4];
  const unsigned short* qrow = Q + ((size_t)((b*SEQL + q0w + lr)*NH) + h)*HD;
  #pragma unroll
  for(int ds=0;ds<4;ds++) qf[ds] = *reinterpret_cast<const bfx8*>(qrow + ds*32 + lg*8);

  f32x4 z = {0.f,0.f,0.f,0.f};
  f32x4 oacc[8];
  #pragma unroll
  for(int i=0;i<8;i++) oacc[i] = z;
  float m_run = -1e30f, l_run = 0.f;

  int srow = t>>3, sch = t&7;                // 8 lanes per row: conflict-free by group
  int ntile = qt + 1;
  for(int tl=0; tl<ntile; ++tl){
    int k0 = tl << 6;
    __syncthreads();
    // stage K: 64 rows x 16 chunks (2 row-passes x 2 chunk-passes)
    #pragma unroll
    for(int pr=0;pr<2;pr++){
      int row = srow + (pr<<5);
      const unsigned short* ks = Kb + ((size_t)((b*SEQL + k0 + row)*NH) + h)*HD;
      #pragma unroll
      for(int pc=0;pc<2;pc++){
        int cl = sch + (pc<<3);
        *reinterpret_cast<bfx8*>((char*)Klds + row*256 + ((cl ^ (row&7))<<4)) =
            *reinterpret_cast<const bfx8*>(ks + cl*8);
      }
    }
    // stage VT: 128 rows x 8 chunks (4 row-passes)
    #pragma unroll
    for(int pr=0;pr<4;pr++){
      int row = srow + (pr<<5);
      const unsigned short* vs = VT + ((size_t)((b*NH + h)*HD + row))*SEQL + k0;
      *reinterpret_cast<bfx8*>((char*)Vlds + row*128 + ((sch ^ (row&7))<<4)) =
          *reinterpret_cast<const bfx8*>(vs + sch*8);
    }
    __syncthreads();

    // QK^T: 4 key-groups of 16
    f32x4 sAcc[4];
    sAcc[0]=z; sAcc[1]=z; sAcc[2]=z; sAcc[3]=z;
    #pragma unroll
    for(int ds=0;ds<4;ds++){
      int cha = (ds<<2) + lg;
      #pragma unroll
      for(int kg=0;kg<4;kg++){
        int row = (kg<<4) + lr;
        bfx8 ka = *reinterpret_cast<const bfx8*>((char*)Klds + row*256 + ((cha ^ (row&7))<<4));
        sAcc[kg] = __builtin_amdgcn_mfma_f32_16x16x32_bf16(ka, qf[ds], sAcc[kg], 0,0,0);
      }
    }
    // online softmax over 64 keys (q = lr, stats replicated over lg after reduce)
    int qg = q0w + lr;
    float p[16];
    float mx = -1e30f;
    #pragma unroll
    for(int kg=0;kg<4;kg++){
      #pragma unroll
      for(int r=0;r<4;r++){
        int kk = k0 + (kg<<4) + (lg<<2) + r;
        float v = (kk <= qg) ? sAcc[kg][r] : -1e30f;
        p[kg*4+r] = v; mx = fmaxf(mx, v);
      }
    }
    mx = fmaxf(mx, __shfl_xor(mx,16));
    mx = fmaxf(mx, __shfl_xor(mx,32));
    float m_new = fmaxf(m_run, mx);
    float fac = __expf(m_run - m_new);
    float ts = 0.f;
    #pragma unroll
    for(int i=0;i<16;i++){ p[i] = __expf(p[i]-m_new); ts += p[i]; }
    ts += __shfl_xor(ts,16); ts += __shfl_xor(ts,32);
    l_run = l_run*fac + ts;
    m_run = m_new;
    // P -> per-wave LDS (bf16), row q = lr, keys kg*16 + lg*4 + r
    char* pb = (char*)&Plds[w][0] + lr*144 + lg*8;
    #pragma unroll
    for(int kg=0;kg<4;kg++){
      unsigned pa = (unsigned)f2bf(p[kg*4+0]) | ((unsigned)f2bf(p[kg*4+1])<<16);
      unsigned pc = (unsigned)f2bf(p[kg*4+2]) | ((unsigned)f2bf(p[kg*4+3])<<16);
      *reinterpret_cast<uint2*>(pb + kg*32) = make_uint2(pa, pc);
    }
    // rescale O (D-frag rows = q = lg*4+r; stats live at lane q)
    float facr[4];
    #pragma unroll
    for(int r=0;r<4;r++) facr[r] = __shfl(fac, (lg<<2)+r);
    #pragma unroll
    for(int db=0;db<8;db++){
      f32x4 o = oacc[db];
      o[0]*=facr[0]; o[1]*=facr[1]; o[2]*=facr[2]; o[3]*=facr[3];
      oacc[db] = o;
    }
    // PV: O[q][d] += P[q][k] * V[k][d]; B-operand from VT (rows d)
    #pragma unroll
    for(int kh=0;kh<2;kh++){
      bfx8 pf = *reinterpret_cast<const bfx8*>((char*)&Plds[w][0] + lr*144 + kh*64 + lg*16);
      #pragma unroll
      for(int db=0;db<8;db++){
        int row = (db<<4) + lr;
        int lc = (kh<<2) + lg;
        bfx8 vf = *reinterpret_cast<const bfx8*>((char*)Vlds + row*128 + ((lc ^ (row&7))<<4));
        oacc[db] = __builtin_amdgcn_mfma_f32_16x16x32_bf16(pf, vf, oacc[db], 0,0,0);
      }
    }
  }
  float lsr[4];
  #pragma unroll
  for(int r=0;r<4;r++) lsr[r] = 1.0f / __shfl(l_run, (lg<<2)+r);
  #pragma unroll
  for(int db=0;db<8;db++){
    #pragma unroll
    for(int r=0;r<4;r++){
      int row = q0w + (lg<<2) + r;
      O[((size_t)((b*SEQL + row)*NH) + h)*HD + (db<<4) + lr] = f2bf(oacc[db][r]*lsr[r]);
    }
  }
}

// ---------------- host launcher ----------------
// Workspace plan (129 MB, overlaid; same-stream ordering makes reuse safe):
//   Wbuf 32MB (weight staging, reused) | hb 16 | qb 16 | kb 16 | vb 16 | aob 16 |
//   x1 32 (fp32 residual; its first 16MB doubles as VT during attention) | tables 1
extern "C" void kernel_launch(void* const* d_in, const int* in_sizes, int n_in,
                              void* d_out, int out_size, void* d_ws, size_t ws_size,
                              hipStream_t stream){
  const float* x   = (const float*)d_in[0];
  const float* anw = (const float*)d_in[1];
  const float* qw  = (const float*)d_in[2];
  const float* kw  = (const float*)d_in[3];
  const float* vw  = (const float*)d_in[4];
  const float* ow  = (const float*)d_in[5];
  const float* fnw = (const float*)d_in[6];
  const float* gw  = (const float*)d_in[7];
  const float* uw  = (const float*)d_in[8];
  const float* dw  = (const float*)d_in[9];
  float* out = (float*)d_out;

  char* ws = (char*)d_ws;
  size_t off = 0;
  auto alloc = [&](size_t bytes)->char*{ char* p = ws + off; off += (bytes + 255) & ~(size_t)255; return p; };
  unsigned short* Wbuf = (unsigned short*)alloc((size_t)INTERD*HID*2);   // 32 MB, reused
  unsigned short* hb   = (unsigned short*)alloc((size_t)NTOK*HID*2);     // 16 MB
  unsigned short* qb   = (unsigned short*)alloc((size_t)NTOK*HID*2);     // 16 MB
  unsigned short* kb   = (unsigned short*)alloc((size_t)NTOK*HID*2);     // 16 MB
  unsigned short* vb   = (unsigned short*)alloc((size_t)NTOK*HID*2);     // 16 MB
  unsigned short* aob  = (unsigned short*)alloc((size_t)NTOK*HID*2);     // 16 MB
  float*          x1   = (float*)alloc((size_t)NTOK*HID*4);              // 32 MB
  float*          cosb = (float*)alloc((size_t)SEQL*64*4);
  float*          sinb = (float*)alloc((size_t)SEQL*64*4);
  unsigned short* gb   = qb;                  // 64 MB overlay: qb|kb|vb|aob dead after O-proj
  unsigned short* VT   = (unsigned short*)x1; // 16 MB overlay: x1 written only after attn
  if(ws_size < off){ k_sentinel<<<1,1,0,stream>>>(out); return; }

  k_ropetab<<<SEQL, 64, 0, stream>>>(cosb, sinb);

  // ---- attention sublayer ----
  k_rmsnorm<<<NTOK, 256, 0, stream>>>(x, anw, hb);
  k_cvt<<<HID*HID/1024, 256, 0, stream>>>(qw, Wbuf, HID*HID/4);
  k_gemm<0><<<(NTOK/128)*(HID/128), 256, 0, stream>>>(hb, Wbuf, qb, nullptr, nullptr, NTOK, HID, HID);
  k_cvt<<<HID*HID/1024, 256, 0, stream>>>(kw, Wbuf, HID*HID/4);
  k_gemm<0><<<(NTOK/128)*(HID/128), 256, 0, stream>>>(hb, Wbuf, kb, nullptr, nullptr, NTOK, HID, HID);
  k_cvt<<<HID*HID/1024, 256, 0, stream>>>(vw, Wbuf, HID*HID/4);
  k_gemm<0><<<(NTOK/128)*(HID/128), 256, 0, stream>>>(hb, Wbuf, vb, nullptr, nullptr, NTOK, HID, HID);
  k_transpose_v<<<NBATCH*NH*(SEQL/64), 256, 0, stream>>>(vb, VT);
  k_rope<<<(NTOK*NH*64)/256, 256, 0, stream>>>(qb, cosb, sinb, 0.08838834764831845f); // 1/sqrt(128)
  k_rope<<<(NTOK*NH*64)/256, 256, 0, stream>>>(kb, cosb, sinb, 1.0f);
  k_attn<<<(SEQL/64)*NBATCH*NH, 256, 0, stream>>>(qb, kb, VT, aob);
  k_cvt<<<HID*HID/1024, 256, 0, stream>>>(ow, Wbuf, HID*HID/4);
  k_gemm<1><<<(NTOK/128)*(HID/128), 256, 0, stream>>>(aob, Wbuf, x1, x, nullptr, NTOK, HID, HID);

  // ---- MLP sublayer ----
  k_rmsnorm<<<NTOK, 256, 0, stream>>>(x1, fnw, hb);
  k_cvt<<<INTERD*HID/1024, 256, 0, stream>>>(gw, Wbuf, INTERD*HID/4);
  k_gemm<0><<<(NTOK/128)*(INTERD/128), 256, 0, stream>>>(hb, Wbuf, gb, nullptr, nullptr, NTOK, INTERD, HID);
  k_cvt<<<INTERD*HID/1024, 256, 0, stream>>>(uw, Wbuf, INTERD*HID/4);
  k_gemm<2><<<(NTOK/128)*(INTERD/128), 256, 0, stream>>>(hb, Wbuf, gb, nullptr, gb, NTOK, INTERD, HID);
  k_cvt<<<INTERD*HID/1024, 256, 0, stream>>>(dw, Wbuf, INTERD*HID/4);
  k_gemm<1><<<(NTOK/128)*(HID/128), 256, 0, stream>>>(gb, Wbuf, out, x1, nullptr, NTOK, HID, INTERD);
}

// Round 4
// 894.631 us; speedup vs baseline: 1.2914x; 1.1157x over previous
//
#include <hip/hip_runtime.h>
#include <math.h>

#define HID 2048
#define NH 16
#define HD 128
#define INTERD 8192
#define SEQL 2048
#define NBATCH 2
#define NTOK (NBATCH*SEQL)

typedef float f32x4 __attribute__((ext_vector_type(4)));
typedef __bf16 bfx8 __attribute__((ext_vector_type(8)));

__device__ __forceinline__ float bf2f(unsigned short u){
  union { float f; unsigned v; } c; c.v = ((unsigned)u)<<16; return c.f;
}
__device__ __forceinline__ unsigned short f2bf(float f){
  union { float f; unsigned v; } c; c.f = f;
  unsigned r = c.v + 0x7FFFu + ((c.v>>16)&1u);   // RNE
  return (unsigned short)(r>>16);
}

// async global->LDS, 16B per lane; LDS dest = wave-uniform base + lane*16.
// (proven working in round 3: absmax unchanged, SQ_LDS_BANK_CONFLICT=0)
__device__ __forceinline__ void gll16(const unsigned short* g, void* l){
  __builtin_amdgcn_global_load_lds(
      (const __attribute__((address_space(1))) unsigned int*)(size_t)(const void*)g,
      (__attribute__((address_space(3))) unsigned int*)(unsigned int)(size_t)l,
      16, 0, 0);
}

// ---------------- sentinel: marks "workspace too small" unambiguously ----------------
__global__ void k_sentinel(float* out){ out[0] = 1.0e9f; }

// ---------------- fp32 -> bf16 conversion (weights) ----------------
__global__ __launch_bounds__(256) void k_cvt(const float* __restrict__ in,
                                             unsigned short* __restrict__ out, int n4){
  int i = blockIdx.x*256 + threadIdx.x;
  if(i >= n4) return;
  float4 v = reinterpret_cast<const float4*>(in)[i];
  ushort4 o;
  o.x = f2bf(v.x); o.y = f2bf(v.y); o.z = f2bf(v.z); o.w = f2bf(v.w);
  reinterpret_cast<ushort4*>(out)[i] = o;
}

// ---------------- RMSNorm (fp32 in) -> bf16 out ----------------
__global__ __launch_bounds__(256) void k_rmsnorm(const float* __restrict__ x,
                                                 const float* __restrict__ w,
                                                 unsigned short* __restrict__ out){
  int row = blockIdx.x, t = threadIdx.x;
  const float4* xr = reinterpret_cast<const float4*>(x + (size_t)row*HID);
  float4 a = xr[2*t], b = xr[2*t+1];
  float ss = a.x*a.x+a.y*a.y+a.z*a.z+a.w*a.w + b.x*b.x+b.y*b.y+b.z*b.z+b.w*b.w;
  #pragma unroll
  for(int o=1;o<64;o<<=1) ss += __shfl_xor(ss, o);
  __shared__ float red[4];
  if((t&63)==0) red[t>>6] = ss;
  __syncthreads();
  float sc = rsqrtf((red[0]+red[1]+red[2]+red[3])*(1.0f/HID) + 1e-6f);
  const float4* wr = reinterpret_cast<const float4*>(w);
  float4 wa = wr[2*t], wb = wr[2*t+1];
  ushort4 o1, o2;
  o1.x=f2bf(a.x*sc*wa.x); o1.y=f2bf(a.y*sc*wa.y); o1.z=f2bf(a.z*sc*wa.z); o1.w=f2bf(a.w*sc*wa.w);
  o2.x=f2bf(b.x*sc*wb.x); o2.y=f2bf(b.y*sc*wb.y); o2.z=f2bf(b.z*sc*wb.z); o2.w=f2bf(b.w*sc*wb.w);
  ushort4* orow = reinterpret_cast<ushort4*>(out + (size_t)row*HID);
  orow[2*t] = o1; orow[2*t+1] = o2;
}

// ---------------- RoPE tables: cos/sin [SEQL][64] ----------------
__global__ void k_ropetab(float* __restrict__ cs, float* __restrict__ sn){
  int s = blockIdx.x, j = threadIdx.x;   // 64 threads
  float invf = powf(10000.0f, -(float)j*(1.0f/64.0f));
  float ang = (float)s * invf;
  float c, si;
  sincosf(ang, &si, &c);
  cs[s*64+j] = c; sn[s*64+j] = si;
}

// ---------------- RoPE apply in-place on bf16 [tok][ld] at head offset; ----------------
__global__ __launch_bounds__(256) void k_rope(unsigned short* qk, int ld,
                                              const float* __restrict__ cs,
                                              const float* __restrict__ sn, float scale){
  int gid = blockIdx.x*256 + threadIdx.x;
  int j = gid & 63;
  int rh = gid >> 6;               // tok*NH + h
  int tok = rh >> 4, h = rh & 15;
  int s = tok & (SEQL-1);
  unsigned short* base = qk + (size_t)tok*ld + h*HD;
  float c = cs[s*64+j], sv = sn[s*64+j];
  float x1 = bf2f(base[j]), x2 = bf2f(base[j+64]);
  base[j]    = f2bf((x1*c - x2*sv)*scale);
  base[j+64] = f2bf((x2*c + x1*sv)*scale);
}

// ---------------- V transpose: VT[b,h,d,s] <- V[tok][ld] (bf16) ----------------
__global__ __launch_bounds__(256) void k_transpose_v(const unsigned short* __restrict__ V,
                                                     int ld,
                                                     unsigned short* __restrict__ VT){
  __shared__ unsigned short T[64*136];   // [s][d], stride 136 hw
  int bid = blockIdx.x;
  int sb = bid & 31, h = (bid>>5) & 15, b = bid>>9;
  int t = threadIdx.x;
  int s0 = sb<<6;
  int sl = t>>2, dc = (t&3)<<5;
  const unsigned short* src = V + (size_t)(b*SEQL + s0 + sl)*ld + h*HD + dc;
  #pragma unroll
  for(int p=0;p<4;p++){
    bfx8 v = *reinterpret_cast<const bfx8*>(src + p*8);
    *reinterpret_cast<bfx8*>(&T[sl*136 + dc + p*8]) = v;
  }
  __syncthreads();
  int d = t>>1, sh = (t&1)<<5;
  unsigned short* dst = VT + ((size_t)((b*NH + h)*HD + d))*SEQL + s0 + sh;
  #pragma unroll
  for(int p=0;p<4;p++){
    union { bfx8 v; unsigned short u[8]; } o;
    #pragma unroll
    for(int j=0;j<8;j++) o.u[j] = T[(sh + p*8 + j)*136 + d];
    *reinterpret_cast<bfx8*>(dst + p*8) = o.v;
  }
}

// ==================== GEMM: C[M,N] = A[M,K] * W[N,K]^T, 8-phase-style pipeline =========
// BM=256, BN=128, BK=64; 512 thr = 8 waves (4M x 2N), wave-tile 64x64 (4x4 16x16 frags).
// Triple-buffered LDS (144KB), prefetch distance 2 K-tiles, counted vmcnt(6) once/K-tile,
// 2 phases per K-tile: {ds_read || 3x gll16 stage; bar; lgkmcnt0; setprio1; 16 MFMA; bar}.
// LDS swizzle: 16B-chunk ^ (row&7), applied via pre-swizzled global source (rule #21).
// EPI 0: bf16.  EPI 1: fp32 = resid + acc.  EPI 2: bf16 = silu(gbuf)*acc.
template<int EPI>
__global__ __launch_bounds__(512, 2) void k_gemm(const unsigned short* __restrict__ A,
                                                 const unsigned short* __restrict__ W,
                                                 void* out, const float* __restrict__ resid,
                                                 const unsigned short* gbuf,
                                                 int M, int N, int K){
  __shared__ unsigned short Alds[3][256*64];   // 96 KB
  __shared__ unsigned short Blds[3][128*64];   // 48 KB
  int nwg = gridDim.x;
  int bid = blockIdx.x;
  bid = (bid & 7)*(nwg>>3) + (bid>>3);     // XCD-aware swizzle (all grids %8==0)
  int nbn = N >> 7;
  int bm0 = (bid / nbn) << 8, bn0 = (bid % nbn) << 7;
  int t = threadIdx.x, w = t>>6, l = t&63, lr = l&15, lg = l>>4;
  int wm = w>>1, wn = w&1;
  int lrow = l>>3, scc = (l&7) ^ lrow;      // pre-swizzled source chunk (involution)
  int nt = K >> 6;

  f32x4 z = {0.f,0.f,0.f,0.f};
  f32x4 acc[4][4];
  #pragma unroll
  for(int i=0;i<4;i++){ acc[i][0]=z; acc[i][1]=z; acc[i][2]=z; acc[i][3]=z; }

  // ---- staging helpers (3 gll per thread per phase; 6 per K-tile) ----
  // A issue j (0..3): rows j*64 + w*8 + lrow of the 256-row tile
  // B issue j (0..1): rows j*64 + w*8 + lrow of the 128-row tile
  #define STAGE_A(buf, j, k0) \
    gll16(A + (size_t)(bm0 + (j)*64 + w*8 + lrow)*K + (k0) + scc*8, \
          (char*)(buf) + ((j)*64 + w*8)*128)
  #define STAGE_B(buf, j, k0) \
    gll16(W + (size_t)(bn0 + (j)*64 + w*8 + lrow)*K + (k0) + scc*8, \
          (char*)(buf) + ((j)*64 + w*8)*128)

  // prologue: stage K-tiles 0 and 1 (12 issues), drain tile 0, keep tile 1 in flight
  #pragma unroll
  for(int pt=0; pt<2; ++pt){
    int k0 = pt<<6;
    STAGE_A(Alds[pt],0,k0); STAGE_A(Alds[pt],1,k0);
    STAGE_A(Alds[pt],2,k0); STAGE_A(Alds[pt],3,k0);
    STAGE_B(Blds[pt],0,k0); STAGE_B(Blds[pt],1,k0);
  }
  asm volatile("s_waitcnt vmcnt(6)" ::: "memory");
  __builtin_amdgcn_s_barrier();

  int cur = 0;
  for(int kt=0; kt<nt; ++kt){
    int pf = cur+2; if(pf>=3) pf-=3;            // prefetch buffer (dead: last read was tile kt-1)
    int kp = kt+2; if(kp>=nt) kp-=nt;           // wrap: last 2 iters stage dead-but-valid data
    int kpk = kp<<6;
    const char* Ac = (const char*)Alds[cur];
    const char* Bc = (const char*)Blds[cur];

    // ---------- phase A: A-frags + B n-half 0; MFMA 16 ----------
    bfx8 af[4][2], bfr[2][2];
    #pragma unroll
    for(int fm=0;fm<4;fm++){
      int row = wm*64 + fm*16 + lr;
      #pragma unroll
      for(int ks=0;ks<2;ks++)
        af[fm][ks] = *reinterpret_cast<const bfx8*>(Ac + row*128 + ((((ks<<2)+lg) ^ (row&7))<<4));
    }
    #pragma unroll
    for(int fn=0;fn<2;fn++){
      int row = wn*64 + fn*16 + lr;
      #pragma unroll
      for(int ks=0;ks<2;ks++)
        bfr[fn][ks] = *reinterpret_cast<const bfx8*>(Bc + row*128 + ((((ks<<2)+lg) ^ (row&7))<<4));
    }
    STAGE_A(Alds[pf],0,kpk); STAGE_A(Alds[pf],1,kpk); STAGE_A(Alds[pf],2,kpk);
    __builtin_amdgcn_s_barrier();
    asm volatile("s_waitcnt lgkmcnt(0)" ::: "memory");
    __builtin_amdgcn_sched_barrier(0);
    __builtin_amdgcn_s_setprio(1);
    #pragma unroll
    for(int fm=0;fm<4;fm++)
      #pragma unroll
      for(int fn=0;fn<2;fn++)
        #pragma unroll
        for(int ks=0;ks<2;ks++)
          acc[fm][fn] = __builtin_amdgcn_mfma_f32_16x16x32_bf16(af[fm][ks], bfr[fn][ks], acc[fm][fn], 0,0,0);
    __builtin_amdgcn_s_setprio(0);
    __builtin_amdgcn_s_barrier();

    // ---------- phase B: B n-half 1; MFMA 16 ----------
    #pragma unroll
    for(int fn=0;fn<2;fn++){
      int row = wn*64 + 32 + fn*16 + lr;
      #pragma unroll
      for(int ks=0;ks<2;ks++)
        bfr[fn][ks] = *reinterpret_cast<const bfx8*>(Bc + row*128 + ((((ks<<2)+lg) ^ (row&7))<<4));
    }
    STAGE_A(Alds[pf],3,kpk); STAGE_B(Blds[pf],0,kpk); STAGE_B(Blds[pf],1,kpk);
    __builtin_amdgcn_s_barrier();
    asm volatile("s_waitcnt lgkmcnt(0)" ::: "memory");
    __builtin_amdgcn_sched_barrier(0);
    __builtin_amdgcn_s_setprio(1);
    #pragma unroll
    for(int fm=0;fm<4;fm++)
      #pragma unroll
      for(int fn=0;fn<2;fn++)
        #pragma unroll
        for(int ks=0;ks<2;ks++)
          acc[fm][2+fn] = __builtin_amdgcn_mfma_f32_16x16x32_bf16(af[fm][ks], bfr[fn][ks], acc[fm][2+fn], 0,0,0);
    __builtin_amdgcn_s_setprio(0);
    // counted drain: tile kt+1's 6 loads (issued during kt-1) must land; leave tile kt+2's 6.
    asm volatile("s_waitcnt vmcnt(6)" ::: "memory");
    __builtin_amdgcn_s_barrier();

    cur = cur+1==3 ? 0 : cur+1;
  }
  #undef STAGE_A
  #undef STAGE_B

  // epilogue: row = bm0 + wm*64 + fm*16 + lg*4 + rr ; col = bn0 + wn*64 + fn*16 + lr
  #pragma unroll
  for(int fm=0;fm<4;fm++){
    #pragma unroll
    for(int rr=0;rr<4;rr++){
      int row = bm0 + wm*64 + fm*16 + (lg<<2) + rr;
      #pragma unroll
      for(int fn=0;fn<4;fn++){
        int col = bn0 + wn*64 + fn*16 + lr;
        size_t idx = (size_t)row*N + col;
        float v = acc[fm][fn][rr];
        if(EPI==0){
          reinterpret_cast<unsigned short*>(out)[idx] = f2bf(v);
        } else if(EPI==1){
          reinterpret_cast<float*>(out)[idx] = resid[idx] + v;
        } else {
          float g = bf2f(gbuf[idx]);
          float sg = g / (1.0f + __expf(-g));
          reinterpret_cast<unsigned short*>(out)[idx] = f2bf(sg*v);
        }
      }
    }
  }
}

// ---------------- Flash attention, causal. Q/K bf16 [tok][ldqk] at head offset
// (RoPE'd, Q pre-scaled), V^T bf16 [B,H,D,S]. 256 thr = 4 waves; 64 q/block; KV tile 64.
__global__ __launch_bounds__(256) void k_attn(const unsigned short* __restrict__ Q,
                                              const unsigned short* __restrict__ Kb,
                                              int ldqk,
                                              const unsigned short* __restrict__ VT,
                                              unsigned short* __restrict__ O){
  __shared__ unsigned short Klds[64*128];     // [key][d] swizzled: 16 chunks/row, c^(row&7)
  __shared__ unsigned short Vlds[128*64];     // [d][key] swizzled: 8 chunks/row, c^(row&7)
  __shared__ unsigned short Plds[4][16*72];   // per-wave P[q][key], stride 72 hw

  int bid = blockIdx.x;
  int xcd = bid & 7, idx = bid >> 3;
  int bh = xcd*4 + (idx & 3);
  int qt = 31 - (idx >> 2);
  int h = bh & 15, b = bh >> 4;
  int q0 = qt << 6;
  int t = threadIdx.x, w = t>>6, l = t&63, lr = l&15, lg = l>>4;
  int q0w = q0 + (w<<4);

  bfx8 qf[4];
  const unsigned short* qrow = Q + (size_t)(b*SEQL + q0w + lr)*ldqk + h*HD;
  #pragma unroll
  for(int ds=0;ds<4;ds++) qf[ds] = *reinterpret_cast<const bfx8*>(qrow + ds*32 + lg*8);

  f32x4 z = {0.f,0.f,0.f,0.f};
  f32x4 oacc[8];
  #pragma unroll
  for(int i=0;i<8;i++) oacc[i] = z;
  float m_run = -1e30f, l_run = 0.f;

  int srow = t>>3, sch = t&7;
  int ntile = qt + 1;
  for(int tl=0; tl<ntile; ++tl){
    int k0 = tl << 6;
    __syncthreads();
    #pragma unroll
    for(int pr=0;pr<2;pr++){
      int row = srow + (pr<<5);
      const unsigned short* ks = Kb + (size_t)(b*SEQL + k0 + row)*ldqk + h*HD;
      #pragma unroll
      for(int pc=0;pc<2;pc++){
        int cl = sch + (pc<<3);
        *reinterpret_cast<bfx8*>((char*)Klds + row*256 + ((cl ^ (row&7))<<4)) =
            *reinterpret_cast<const bfx8*>(ks + cl*8);
      }
    }
    #pragma unroll
    for(int pr=0;pr<4;pr++){
      int row = srow + (pr<<5);
      const unsigned short* vs = VT + ((size_t)((b*NH + h)*HD + row))*SEQL + k0;
      *reinterpret_cast<bfx8*>((char*)Vlds + row*128 + ((sch ^ (row&7))<<4)) =
          *reinterpret_cast<const bfx8*>(vs + sch*8);
    }
    __syncthreads();

    f32x4 sAcc[4];
    sAcc[0]=z; sAcc[1]=z; sAcc[2]=z; sAcc[3]=z;
    #pragma unroll
    for(int ds=0;ds<4;ds++){
      int cha = (ds<<2) + lg;
      #pragma unroll
      for(int kg=0;kg<4;kg++){
        int row = (kg<<4) + lr;
        bfx8 ka = *reinterpret_cast<const bfx8*>((char*)Klds + row*256 + ((cha ^ (row&7))<<4));
        sAcc[kg] = __builtin_amdgcn_mfma_f32_16x16x32_bf16(ka, qf[ds], sAcc[kg], 0,0,0);
      }
    }
    int qg = q0w + lr;
    float p[16];
    float mx = -1e30f;
    #pragma unroll
    for(int kg=0;kg<4;kg++){
      #pragma unroll
      for(int r=0;r<4;r++){
        int kk = k0 + (kg<<4) + (lg<<2) + r;
        float v = (kk <= qg) ? sAcc[kg][r] : -1e30f;
        p[kg*4+r] = v; mx = fmaxf(mx, v);
      }
    }
    mx = fmaxf(mx, __shfl_xor(mx,16));
    mx = fmaxf(mx, __shfl_xor(mx,32));
    float m_new = fmaxf(m_run, mx);
    float fac = __expf(m_run - m_new);
    float ts = 0.f;
    #pragma unroll
    for(int i=0;i<16;i++){ p[i] = __expf(p[i]-m_new); ts += p[i]; }
    ts += __shfl_xor(ts,16); ts += __shfl_xor(ts,32);
    l_run = l_run*fac + ts;
    m_run = m_new;
    char* pb = (char*)&Plds[w][0] + lr*144 + lg*8;
    #pragma unroll
    for(int kg=0;kg<4;kg++){
      unsigned pa = (unsigned)f2bf(p[kg*4+0]) | ((unsigned)f2bf(p[kg*4+1])<<16);
      unsigned pc = (unsigned)f2bf(p[kg*4+2]) | ((unsigned)f2bf(p[kg*4+3])<<16);
      *reinterpret_cast<uint2*>(pb + kg*32) = make_uint2(pa, pc);
    }
    float facr[4];
    #pragma unroll
    for(int r=0;r<4;r++) facr[r] = __shfl(fac, (lg<<2)+r);
    #pragma unroll
    for(int db=0;db<8;db++){
      f32x4 o = oacc[db];
      o[0]*=facr[0]; o[1]*=facr[1]; o[2]*=facr[2]; o[3]*=facr[3];
      oacc[db] = o;
    }
    __syncthreads();
    #pragma unroll
    for(int kh=0;kh<2;kh++){
      bfx8 pf = *reinterpret_cast<const bfx8*>((char*)&Plds[w][0] + lr*144 + kh*64 + lg*16);
      #pragma unroll
      for(int db=0;db<8;db++){
        int row = (db<<4) + lr;
        int lc = (kh<<2) + lg;
        bfx8 vf = *reinterpret_cast<const bfx8*>((char*)Vlds + row*128 + ((lc ^ (row&7))<<4));
        oacc[db] = __builtin_amdgcn_mfma_f32_16x16x32_bf16(pf, vf, oacc[db], 0,0,0);
      }
    }
  }
  float lsr[4];
  #pragma unroll
  for(int r=0;r<4;r++) lsr[r] = 1.0f / __shfl(l_run, (lg<<2)+r);
  #pragma unroll
  for(int db=0;db<8;db++){
    #pragma unroll
    for(int r=0;r<4;r++){
      int row = q0w + (lg<<2) + r;
      O[((size_t)((b*SEQL + row)*NH) + h)*HD + (db<<4) + lr] = f2bf(oacc[db][r]*lsr[r]);
    }
  }
}

// ---------------- host launcher ----------------
// Workspace (145 MB, same footprint that passed in rounds 2-3):
//   Wbuf 32MB (bf16 weight staging; QKV fused = 24MB) | hb 16 | qkvb 48 ([4096][6144]:
//   q|k|v column blocks) | aob 16 | x1 32 (fp32 residual; first 16MB doubles as VT) | tables 1
//   gb (gate/h_mid, [4096][8192] = 64MB) overlays qkvb+aob (dead after O-proj).
extern "C" void kernel_launch(void* const* d_in, const int* in_sizes, int n_in,
                              void* d_out, int out_size, void* d_ws, size_t ws_size,
                              hipStream_t stream){
  const float* x   = (const float*)d_in[0];
  const float* anw = (const float*)d_in[1];
  const float* qw  = (const float*)d_in[2];
  const float* kw  = (const float*)d_in[3];
  const float* vw  = (const float*)d_in[4];
  const float* ow  = (const float*)d_in[5];
  const float* fnw = (const float*)d_in[6];
  const float* gw  = (const float*)d_in[7];
  const float* uw  = (const float*)d_in[8];
  const float* dw  = (const float*)d_in[9];
  float* out = (float*)d_out;

  char* ws = (char*)d_ws;
  size_t off = 0;
  auto alloc = [&](size_t bytes)->char*{ char* p = ws + off; off += (bytes + 255) & ~(size_t)255; return p; };
  unsigned short* Wbuf = (unsigned short*)alloc((size_t)INTERD*HID*2);     // 32 MB
  unsigned short* hb   = (unsigned short*)alloc((size_t)NTOK*HID*2);       // 16 MB
  unsigned short* qkvb = (unsigned short*)alloc((size_t)NTOK*3*HID*2);     // 48 MB
  unsigned short* aob  = (unsigned short*)alloc((size_t)NTOK*HID*2);       // 16 MB
  float*          x1   = (float*)alloc((size_t)NTOK*HID*4);                // 32 MB
  float*          cosb = (float*)alloc((size_t)SEQL*64*4);
  float*          sinb = (float*)alloc((size_t)SEQL*64*4);
  unsigned short* gb   = qkvb;                // 64 MB overlay (qkvb+aob), dead after O-proj
  unsigned short* VT   = (unsigned short*)x1; // 16 MB overlay: x1 written only after attn
  if(ws_size < off){ k_sentinel<<<1,1,0,stream>>>(out); return; }

  k_ropetab<<<SEQL, 64, 0, stream>>>(cosb, sinb);

  // ---- attention sublayer ----
  k_rmsnorm<<<NTOK, 256, 0, stream>>>(x, anw, hb);
  k_cvt<<<HID*HID/1024, 256, 0, stream>>>(qw, Wbuf,             HID*HID/4);
  k_cvt<<<HID*HID/1024, 256, 0, stream>>>(kw, Wbuf +   HID*HID, HID*HID/4);
  k_cvt<<<HID*HID/1024, 256, 0, stream>>>(vw, Wbuf + 2*HID*HID, HID*HID/4);
  k_gemm<0><<<(NTOK/256)*(3*HID/128), 512, 0, stream>>>(hb, Wbuf, qkvb, nullptr, nullptr, NTOK, 3*HID, HID); // 768 blk
  k_rope<<<(NTOK*NH*64)/256, 256, 0, stream>>>(qkvb,        3*HID, cosb, sinb, 0.08838834764831845f);
  k_rope<<<(NTOK*NH*64)/256, 256, 0, stream>>>(qkvb +  HID, 3*HID, cosb, sinb, 1.0f);
  k_transpose_v<<<NBATCH*NH*(SEQL/64), 256, 0, stream>>>(qkvb + 2*HID, 3*HID, VT);
  k_attn<<<(SEQL/64)*NBATCH*NH, 256, 0, stream>>>(qkvb, qkvb + HID, 3*HID, VT, aob);
  k_cvt<<<HID*HID/1024, 256, 0, stream>>>(ow, Wbuf, HID*HID/4);
  k_gemm<1><<<(NTOK/256)*(HID/128), 512, 0, stream>>>(aob, Wbuf, x1, x, nullptr, NTOK, HID, HID);            // 256 blk

  // ---- MLP sublayer ----
  k_rmsnorm<<<NTOK, 256, 0, stream>>>(x1, fnw, hb);
  k_cvt<<<INTERD*HID/1024, 256, 0, stream>>>(gw, Wbuf, INTERD*HID/4);
  k_gemm<0><<<(NTOK/256)*(INTERD/128), 512, 0, stream>>>(hb, Wbuf, gb, nullptr, nullptr, NTOK, INTERD, HID); // 1024 blk
  k_cvt<<<INTERD*HID/1024, 256, 0, stream>>>(uw, Wbuf, INTERD*HID/4);
  k_gemm<2><<<(NTOK/256)*(INTERD/128), 512, 0, stream>>>(hb, Wbuf, gb, nullptr, gb, NTOK, INTERD, HID);
  k_cvt<<<INTERD*HID/1024, 256, 0, stream>>>(dw, Wbuf, INTERD*HID/4);
  k_gemm<1><<<(NTOK/256)*(HID/128), 512, 0, stream>>>(gb, Wbuf, out, x1, nullptr, NTOK, HID, INTERD);        // 256 blk
}